// Round 1
// baseline (17477.071 us; speedup 1.0000x reference)
//
#include <hip/hip_runtime.h>
#include <type_traits>

// ---------------- types ----------------
typedef _Float16 half8 __attribute__((ext_vector_type(8)));
typedef _Float16 half4v __attribute__((ext_vector_type(4)));
typedef float f32x4 __attribute__((ext_vector_type(4)));

#define B_ 64
#define T_ 512
#define H_ 1024
#define G_ 4096      // 4*H
#define K_ 1024
#define MPROJ (B_ * T_)  // 32768

// ---------------- prep kernels ----------------
__global__ void k_f32_to_f16(const float* __restrict__ s, _Float16* __restrict__ d, int n4) {
  int i = blockIdx.x * 256 + threadIdx.x;
  if (i < n4) {
    float4 v = ((const float4*)s)[i];
    half4v o;
    o[0] = (_Float16)v.x; o[1] = (_Float16)v.y; o[2] = (_Float16)v.z; o[3] = (_Float16)v.w;
    ((half4v*)d)[i] = o;
  }
}

__global__ void k_bias(const float* __restrict__ bi0, const float* __restrict__ bh0,
                       const float* __restrict__ bi1, const float* __restrict__ bh1,
                       float* __restrict__ o0, float* __restrict__ o1) {
  int i = blockIdx.x * 256 + threadIdx.x;
  if (i < G_) { o0[i] = bi0[i] + bh0[i]; o1[i] = bi1[i] + bh1[i]; }
}

__global__ void k_zero(uint4* __restrict__ p, int n) {
  int i = blockIdx.x * 256 + threadIdx.x;
  if (i < n) p[i] = make_uint4(0u, 0u, 0u, 0u);
}

// ---------------- projection GEMM ----------------
// C[m][n] = sum_k A[m][k]*Bw[n][k] + bias[n], C stored fp16. M=32768, N=4096, K=1024.
// 128x128 tile, BK=32, 256 thr (4 waves, each a 64x64 quadrant of 4x4 16x16x32 MFMAs).
// LDS row stride 40 halves (80B = 5*16B): ds_read_b128 conflict-free phases.
template <typename AT>
__global__ __launch_bounds__(256, 2) void k_proj(const AT* __restrict__ A,
                                                 const _Float16* __restrict__ Bw,
                                                 const float* __restrict__ bias,
                                                 _Float16* __restrict__ C) {
  const int NBN = G_ / 128;  // 32
  int bm = blockIdx.x / NBN;
  int bn = blockIdx.x % NBN;
  __shared__ __align__(16) _Float16 As[128 * 40];
  __shared__ __align__(16) _Float16 Bs[128 * 40];
  int tid = threadIdx.x;
  int lane = tid & 63, wave = tid >> 6;
  int wm = (wave >> 1) * 64, wn = (wave & 1) * 64;
  int quad = lane >> 4, l16 = lane & 15;
  f32x4 acc[4][4] = {};
  int r = tid >> 1;            // staged row 0..127
  int hc = (tid & 1) * 16;     // half-offset within BK=32
  const AT* aRow = A + (size_t)(bm * 128 + r) * K_ + hc;
  const _Float16* bRow = Bw + (size_t)(bn * 128 + r) * K_ + hc;
  _Float16* aDst = As + r * 40 + hc;
  _Float16* bDst = Bs + r * 40 + hc;

  for (int kt = 0; kt < K_ / 32; ++kt) {
    if constexpr (std::is_same<AT, float>::value) {
      float tmp[16];
      *(float4*)(tmp + 0)  = *(const float4*)(aRow + 0);
      *(float4*)(tmp + 4)  = *(const float4*)(aRow + 4);
      *(float4*)(tmp + 8)  = *(const float4*)(aRow + 8);
      *(float4*)(tmp + 12) = *(const float4*)(aRow + 12);
      half8 h0, h1;
#pragma unroll
      for (int e = 0; e < 8; ++e) { h0[e] = (_Float16)tmp[e]; h1[e] = (_Float16)tmp[e + 8]; }
      *(half8*)(aDst) = h0;
      *(half8*)(aDst + 8) = h1;
    } else {
      *(half8*)(aDst) = *(const half8*)(aRow);
      *(half8*)(aDst + 8) = *(const half8*)(aRow + 8);
    }
    *(half8*)(bDst) = *(const half8*)(bRow);
    *(half8*)(bDst + 8) = *(const half8*)(bRow + 8);
    __syncthreads();
    half8 af[4], bf[4];
#pragma unroll
    for (int i = 0; i < 4; ++i) af[i] = *(const half8*)(As + (wm + i * 16 + l16) * 40 + quad * 8);
#pragma unroll
    for (int j = 0; j < 4; ++j) bf[j] = *(const half8*)(Bs + (wn + j * 16 + l16) * 40 + quad * 8);
#pragma unroll
    for (int i = 0; i < 4; ++i)
#pragma unroll
      for (int j = 0; j < 4; ++j)
        acc[i][j] = __builtin_amdgcn_mfma_f32_16x16x32_f16(af[i], bf[j], acc[i][j], 0, 0, 0);
    __syncthreads();
    aRow += 32;
    bRow += 32;
  }
  // epilogue: C/D layout m = quad*4+reg, n = lane&15 (dtype-independent, m89-verified)
#pragma unroll
  for (int j = 0; j < 4; ++j) {
    int n = bn * 128 + wn + j * 16 + l16;
    float bv = bias[n];
#pragma unroll
    for (int i = 0; i < 4; ++i) {
      size_t m0 = (size_t)(bm * 128 + wm + i * 16 + quad * 4);
#pragma unroll
      for (int rr = 0; rr < 4; ++rr)
        C[(m0 + rr) * G_ + n] = (_Float16)(acc[i][j][rr] + bv);
    }
  }
}

// ---------------- persistent recurrence ----------------
// 256 WGs x 512 thr (cooperative). Group g = blockIdx&3 owns batch rows [16g,16g+16),
// WG wid = blockIdx>>2 owns hidden units [16*wid, 16*wid+16) (all 4 gates).
// W_hh slice lives in registers (16 frags/wave; K split 8-ways over waves).
// c state lives in LDS for the whole kernel. Per-step device barrier per group.
__global__ __launch_bounds__(512, 2) void k_rec(
    const _Float16* __restrict__ xg,   // [B*T][4H] fp16, includes both biases
    const _Float16* __restrict__ Whh,  // [4H][H] fp16
    _Float16* __restrict__ hb0, _Float16* __restrict__ hb1,  // [B][H] ping-pong
    unsigned int* cnt_base,            // per-group monotonic counters (64B apart)
    _Float16* __restrict__ out16,      // layer0: out0 buffer; layer1: null
    float* __restrict__ out32,         // layer1: d_out; layer0: null
    float* __restrict__ hn_out, float* __restrict__ cn_out) {
  int g = blockIdx.x & 3;
  int wid = blockIdx.x >> 2;
  int u0 = wid * 16;
  int b0 = g * 16;
  int tid = threadIdx.x;
  int lane = tid & 63, w = tid >> 6;
  int quad = lane >> 4, l16 = lane & 15;
  unsigned int* cnt = cnt_base + g * 16;

  __shared__ float part[8][4][16][16];  // [wave][gate][m][n] fp32 partials
  __shared__ float red[4][16][16];      // reduced gates
  __shared__ float cs[16][16];          // cell state
  if (tid < 256) ((float*)cs)[tid] = 0.f;

  // resident W_hh fragments: wave w covers K-slice [128w, 128w+128)
  int ks = w * 128;
  half8 wf[4][4];
#pragma unroll
  for (int gt = 0; gt < 4; ++gt)
#pragma unroll
    for (int kk = 0; kk < 4; ++kk)
      wf[gt][kk] = *(const half8*)(Whh + (size_t)(gt * H_ + u0 + l16) * K_ + ks + kk * 32 + quad * 8);
  __syncthreads();

  for (int s = 0; s < T_; ++s) {
    const _Float16* hp = (s & 1) ? hb1 : hb0;
    _Float16* hnx = (s & 1) ? hb0 : hb1;

    // prefetch this step's xg early (only finalization waves need it)
    float pxi = 0.f, pxf = 0.f, pxg = 0.f, pxo = 0.f;
    int fm = (w & 3) * 4 + quad;
    if (w < 4) {
      const _Float16* xr = xg + ((size_t)(b0 + fm) * T_ + s) * G_ + u0 + l16;
      pxi = (float)xr[0];
      pxf = (float)xr[H_];
      pxg = (float)xr[2 * H_];
      pxo = (float)xr[3 * H_];
    }

    f32x4 acc[4] = {};
#pragma unroll
    for (int kk = 0; kk < 4; ++kk) {
      half8 af = *(const half8*)(hp + (size_t)(b0 + l16) * H_ + ks + kk * 32 + quad * 8);
#pragma unroll
      for (int gt = 0; gt < 4; ++gt)
        acc[gt] = __builtin_amdgcn_mfma_f32_16x16x32_f16(af, wf[gt][kk], acc[gt], 0, 0, 0);
    }
#pragma unroll
    for (int gt = 0; gt < 4; ++gt)
#pragma unroll
      for (int rr = 0; rr < 4; ++rr)
        part[w][gt][quad * 4 + rr][l16] = acc[gt][rr];
    __syncthreads();

    {  // cross-wave K reduction: wave w -> gate w&3, row-half w>>2
      int gt = w & 3, rh = w >> 2;
#pragma unroll
      for (int rr = 2 * rh; rr < 2 * rh + 2; ++rr) {
        int m = quad * 4 + rr;
        float sum = part[0][gt][m][l16];
#pragma unroll
        for (int w2 = 1; w2 < 8; ++w2) sum += part[w2][gt][m][l16];
        red[gt][m][l16] = sum;
      }
    }
    __syncthreads();

    if (w < 4) {  // finalization: 4 waves x 64 lanes = 256 (m,n) cells
      int m = fm, n = l16;
      float iv = red[0][m][n] + pxi;
      float fv = red[1][m][n] + pxf;
      float gv = red[2][m][n] + pxg;
      float ov = red[3][m][n] + pxo;
      float si = 1.f / (1.f + __expf(-iv));
      float sf = 1.f / (1.f + __expf(-fv));
      float so = 1.f / (1.f + __expf(-ov));
      float ag = fabsf(gv), eg = __expf(-2.f * ag);
      float tg = (1.f - eg) / (1.f + eg);
      tg = (gv < 0.f) ? -tg : tg;
      float c = sf * cs[m][n] + si * tg;
      cs[m][n] = c;
      float ac = fabsf(c), ec = __expf(-2.f * ac);
      float th = (1.f - ec) / (1.f + ec);
      th = (c < 0.f) ? -th : th;
      float h = so * th;
      size_t oidx = ((size_t)(b0 + m) * T_ + s) * H_ + u0 + n;
      hnx[(size_t)(b0 + m) * H_ + u0 + n] = (_Float16)h;
      if (out16) out16[oidx] = (_Float16)h;
      if (out32) out32[oidx] = h;
      if (s == T_ - 1) {
        hn_out[(size_t)(b0 + m) * H_ + u0 + n] = h;
        cn_out[(size_t)(b0 + m) * H_ + u0 + n] = c;
      }
    }
    __syncthreads();  // drains every wave's vmcnt(0) (stores at L2) before fence

    if (tid == 0) {
      __threadfence();       // release: wbl2 -> h visible device-wide
      atomicAdd(cnt, 1u);    // device-scope by default
      unsigned int tgt = 64u * (unsigned)(s + 1);
      while (__hip_atomic_load(cnt, __ATOMIC_RELAXED, __HIP_MEMORY_SCOPE_AGENT) < tgt)
        __builtin_amdgcn_s_sleep(2);
      __threadfence();       // acquire: inv L1/L2 so next step's h loads are fresh
    }
    __syncthreads();
  }
}

// ---------------- host ----------------
extern "C" void kernel_launch(void* const* d_in, const int* in_sizes, int n_in,
                              void* d_out, int out_size, void* d_ws, size_t ws_size,
                              hipStream_t stream) {
  (void)in_sizes; (void)n_in; (void)out_size;
  const float* X    = (const float*)d_in[0];
  const float* Wih0 = (const float*)d_in[1];
  const float* bih0 = (const float*)d_in[2];
  const float* Whh0 = (const float*)d_in[3];
  const float* bhh0 = (const float*)d_in[4];
  const float* Wih1 = (const float*)d_in[5];
  const float* bih1 = (const float*)d_in[6];
  const float* Whh1 = (const float*)d_in[7];
  const float* bhh1 = (const float*)d_in[8];
  float* out = (float*)d_out;
  char* ws = (char*)d_ws;

  // ws layout (bytes):
  constexpr size_t SZW = (size_t)G_ * K_ * 2;  // 8 MB per packed weight
  constexpr size_t OFF_B0   = 4 * SZW;                       // 33554432
  constexpr size_t OFF_B1   = OFF_B0 + 16384;
  constexpr size_t OFF_CNT  = OFF_B1 + 16384;                // 33587200
  constexpr size_t OFF_HBUF = OFF_CNT + 512;                 // 33587712
  constexpr size_t OFF_OUT0 = OFF_HBUF + 4 * 131072;         // 34112000
  constexpr size_t OFF_XG   = OFF_OUT0 + (size_t)MPROJ * H_ * 2;  // 101220864
  constexpr size_t NEED     = OFF_XG + (size_t)MPROJ * G_ * 2;    // 369656320
  if (ws_size < NEED) return;  // fail visibly rather than corrupt

  _Float16* Wih0h = (_Float16*)(ws + 0 * SZW);
  _Float16* Whh0h = (_Float16*)(ws + 1 * SZW);
  _Float16* Wih1h = (_Float16*)(ws + 2 * SZW);
  _Float16* Whh1h = (_Float16*)(ws + 3 * SZW);
  float* b0s = (float*)(ws + OFF_B0);
  float* b1s = (float*)(ws + OFF_B1);
  unsigned int* cnts = (unsigned int*)(ws + OFF_CNT);
  _Float16* hbase = (_Float16*)(ws + OFF_HBUF);
  _Float16* hb00 = hbase;
  _Float16* hb01 = hbase + 65536;
  _Float16* hb10 = hbase + 131072;
  _Float16* hb11 = hbase + 196608;
  _Float16* out0h = (_Float16*)(ws + OFF_OUT0);
  _Float16* xgp   = (_Float16*)(ws + OFF_XG);

  // prep: pack weights to fp16, fold biases, zero h/counters
  k_f32_to_f16<<<4096, 256, 0, stream>>>(Wih0, Wih0h, G_ * K_ / 4);
  k_f32_to_f16<<<4096, 256, 0, stream>>>(Whh0, Whh0h, G_ * K_ / 4);
  k_f32_to_f16<<<4096, 256, 0, stream>>>(Wih1, Wih1h, G_ * K_ / 4);
  k_f32_to_f16<<<4096, 256, 0, stream>>>(Whh1, Whh1h, G_ * K_ / 4);
  k_bias<<<16, 256, 0, stream>>>(bih0, bhh0, bih1, bhh1, b0s, b1s);
  k_zero<<<129, 256, 0, stream>>>((uint4*)(ws + OFF_CNT), (512 + 4 * 131072) / 16);

  const int projGrid = (MPROJ / 128) * (G_ / 128);  // 8192

  // layer 0
  k_proj<float><<<dim3(projGrid), dim3(256), 0, stream>>>(X, Wih0h, b0s, xgp);
  {
    const _Float16* a0 = xgp;
    const _Float16* a1 = Whh0h;
    _Float16* a2 = hb00;
    _Float16* a3 = hb01;
    unsigned int* a4 = cnts;
    _Float16* a5 = out0h;
    float* a6 = nullptr;
    float* a7 = out + 33554432;            // h_n[0]
    float* a8 = out + 33554432 + 131072;   // c_n[0]
    void* args[9] = {&a0, &a1, &a2, &a3, &a4, &a5, &a6, &a7, &a8};
    hipLaunchCooperativeKernel((void*)k_rec, dim3(256), dim3(512), args, 0, stream);
  }

  // layer 1
  k_proj<_Float16><<<dim3(projGrid), dim3(256), 0, stream>>>(out0h, Wih1h, b1s, xgp);
  {
    const _Float16* a0 = xgp;
    const _Float16* a1 = Whh1h;
    _Float16* a2 = hb10;
    _Float16* a3 = hb11;
    unsigned int* a4 = cnts + 64;
    _Float16* a5 = nullptr;
    float* a6 = out;                               // out1
    float* a7 = out + 33554432 + 65536;            // h_n[1]
    float* a8 = out + 33554432 + 131072 + 65536;   // c_n[1]
    void* args[9] = {&a0, &a1, &a2, &a3, &a4, &a5, &a6, &a7, &a8};
    hipLaunchCooperativeKernel((void*)k_rec, dim3(256), dim3(512), args, 0, stream);
  }
}

// Round 2
// 6953.751 us; speedup vs baseline: 2.5133x; 2.5133x over previous
//
#include <hip/hip_runtime.h>
#include <type_traits>

// ---------------- types ----------------
typedef _Float16 half8 __attribute__((ext_vector_type(8)));
typedef _Float16 half4v __attribute__((ext_vector_type(4)));
typedef float f32x4 __attribute__((ext_vector_type(4)));

struct U128 { unsigned long long a, b; };

#define B_ 64
#define T_ 512
#define H_ 1024
#define G_ 4096      // 4*H
#define K_ 1024
#define MPROJ (B_ * T_)  // 32768

// ---------------- prep kernels ----------------
__global__ void k_f32_to_f16(const float* __restrict__ s, _Float16* __restrict__ d, int n4) {
  int i = blockIdx.x * 256 + threadIdx.x;
  if (i < n4) {
    float4 v = ((const float4*)s)[i];
    half4v o;
    o[0] = (_Float16)v.x; o[1] = (_Float16)v.y; o[2] = (_Float16)v.z; o[3] = (_Float16)v.w;
    ((half4v*)d)[i] = o;
  }
}

__global__ void k_bias(const float* __restrict__ bi0, const float* __restrict__ bh0,
                       const float* __restrict__ bi1, const float* __restrict__ bh1,
                       float* __restrict__ o0, float* __restrict__ o1) {
  int i = blockIdx.x * 256 + threadIdx.x;
  if (i < G_) { o0[i] = bi0[i] + bh0[i]; o1[i] = bi1[i] + bh1[i]; }
}

__global__ void k_zero(uint4* __restrict__ p, int n) {
  int i = blockIdx.x * 256 + threadIdx.x;
  if (i < n) p[i] = make_uint4(0u, 0u, 0u, 0u);
}

// ---------------- projection GEMM ----------------
// C[m][n] = sum_k A[m][k]*Bw[n][k] + bias[n], C stored fp16. M=32768, N=4096, K=1024.
// 128x128 tile, BK=32, 256 thr (4 waves, each a 64x64 quadrant of 4x4 16x16x32 MFMAs).
template <typename AT>
__global__ __launch_bounds__(256, 2) void k_proj(const AT* __restrict__ A,
                                                 const _Float16* __restrict__ Bw,
                                                 const float* __restrict__ bias,
                                                 _Float16* __restrict__ C) {
  const int NBN = G_ / 128;  // 32
  int bm = blockIdx.x / NBN;
  int bn = blockIdx.x % NBN;
  __shared__ __align__(16) _Float16 As[128 * 40];
  __shared__ __align__(16) _Float16 Bs[128 * 40];
  int tid = threadIdx.x;
  int lane = tid & 63, wave = tid >> 6;
  int wm = (wave >> 1) * 64, wn = (wave & 1) * 64;
  int quad = lane >> 4, l16 = lane & 15;
  f32x4 acc[4][4] = {};
  int r = tid >> 1;            // staged row 0..127
  int hc = (tid & 1) * 16;     // half-offset within BK=32
  const AT* aRow = A + (size_t)(bm * 128 + r) * K_ + hc;
  const _Float16* bRow = Bw + (size_t)(bn * 128 + r) * K_ + hc;
  _Float16* aDst = As + r * 40 + hc;
  _Float16* bDst = Bs + r * 40 + hc;

  for (int kt = 0; kt < K_ / 32; ++kt) {
    if constexpr (std::is_same<AT, float>::value) {
      float tmp[16];
      *(float4*)(tmp + 0)  = *(const float4*)(aRow + 0);
      *(float4*)(tmp + 4)  = *(const float4*)(aRow + 4);
      *(float4*)(tmp + 8)  = *(const float4*)(aRow + 8);
      *(float4*)(tmp + 12) = *(const float4*)(aRow + 12);
      half8 h0, h1;
#pragma unroll
      for (int e = 0; e < 8; ++e) { h0[e] = (_Float16)tmp[e]; h1[e] = (_Float16)tmp[e + 8]; }
      *(half8*)(aDst) = h0;
      *(half8*)(aDst + 8) = h1;
    } else {
      *(half8*)(aDst) = *(const half8*)(aRow);
      *(half8*)(aDst + 8) = *(const half8*)(aRow + 8);
    }
    *(half8*)(bDst) = *(const half8*)(bRow);
    *(half8*)(bDst + 8) = *(const half8*)(bRow + 8);
    __syncthreads();
    half8 af[4], bf[4];
#pragma unroll
    for (int i = 0; i < 4; ++i) af[i] = *(const half8*)(As + (wm + i * 16 + l16) * 40 + quad * 8);
#pragma unroll
    for (int j = 0; j < 4; ++j) bf[j] = *(const half8*)(Bs + (wn + j * 16 + l16) * 40 + quad * 8);
#pragma unroll
    for (int i = 0; i < 4; ++i)
#pragma unroll
      for (int j = 0; j < 4; ++j)
        acc[i][j] = __builtin_amdgcn_mfma_f32_16x16x32_f16(af[i], bf[j], acc[i][j], 0, 0, 0);
    __syncthreads();
    aRow += 32;
    bRow += 32;
  }
  // epilogue: C/D layout m = quad*4+reg, n = lane&15
#pragma unroll
  for (int j = 0; j < 4; ++j) {
    int n = bn * 128 + wn + j * 16 + l16;
    float bv = bias[n];
#pragma unroll
    for (int i = 0; i < 4; ++i) {
      size_t m0 = (size_t)(bm * 128 + wm + i * 16 + quad * 4);
#pragma unroll
      for (int rr = 0; rr < 4; ++rr)
        C[(m0 + rr) * G_ + n] = (_Float16)(acc[i][j][rr] + bv);
    }
  }
}

// ---------------- persistent recurrence ----------------
// 256 WGs x 512 thr (cooperative). Group g = blockIdx&3 owns batch rows [16g,16g+16),
// WG wid = blockIdx>>2 owns hidden units [16*wid,16*wid+16) (all 4 gates).
// W_hh slice in registers (K split 8-ways over waves). c state in LDS.
// Cross-WG h exchange is agent-coherent (sc1 stores/loads) — NO cache-wide fences.
// Barrier: per-group monotonic counter; wave0 spins on it (coalesced same-address
// loads), broadcasts via LDS flag; other waves spin on the LDS flag.
__global__ __launch_bounds__(512, 2) void k_rec(
    const _Float16* __restrict__ xg,   // [B*T][4H] fp16, includes both biases
    const _Float16* __restrict__ Whh,  // [4H][H] fp16
    _Float16* __restrict__ hb0, _Float16* __restrict__ hb1,  // [B][H] ping-pong
    unsigned int* cnt_base,            // per-group monotonic counters (64B apart)
    _Float16* __restrict__ out16,      // layer0: out0 buffer; layer1: null
    float* __restrict__ out32,         // layer1: d_out; layer0: null
    float* __restrict__ hn_out, float* __restrict__ cn_out) {
  int g = blockIdx.x & 3;
  int wid = blockIdx.x >> 2;
  int u0 = wid * 16;
  int b0 = g * 16;
  int tid = threadIdx.x;
  int lane = tid & 63, w = tid >> 6;
  int quad = lane >> 4, l16 = lane & 15;
  unsigned int* cnt = cnt_base + g * 16;

  // m-stride padded to 18 floats: all access phases are <=2-way bank aliased (free)
  __shared__ float part[8][4][16][18];  // [wave][gate][m][n]
  __shared__ float red[4][16][18];      // reduced gates
  __shared__ float cs[16][16];          // cell state
  __shared__ int step_flag;
  if (tid < 256) ((float*)cs)[tid] = 0.f;
  if (tid == 0) step_flag = 0;

  // resident W_hh fragments: wave w covers K-slice [128w, 128w+128)
  int ks = w * 128;
  half8 wf[4][4];
#pragma unroll
  for (int gt = 0; gt < 4; ++gt)
#pragma unroll
    for (int kk = 0; kk < 4; ++kk)
      wf[gt][kk] = *(const half8*)(Whh + (size_t)(gt * H_ + u0 + l16) * K_ + ks + kk * 32 + quad * 8);
  __syncthreads();

  for (int s = 0; s < T_; ++s) {
    const _Float16* hp = (s & 1) ? hb1 : hb0;
    _Float16* hnx = (s & 1) ? hb0 : hb1;

    // prefetch this step's xg early (plain loads, L2-cached now)
    float pxi = 0.f, pxf = 0.f, pxg = 0.f, pxo = 0.f;
    int fm = (w & 3) * 4 + quad;
    if (w < 4) {
      const _Float16* xr = xg + ((size_t)(b0 + fm) * T_ + s) * G_ + u0 + l16;
      pxi = (float)xr[0];
      pxf = (float)xr[H_];
      pxg = (float)xr[2 * H_];
      pxo = (float)xr[3 * H_];
    }

    f32x4 acc[4] = {};
#pragma unroll
    for (int kk = 0; kk < 4; ++kk) {
      const _Float16* hsrc = hp + (size_t)(b0 + l16) * H_ + ks + kk * 32 + quad * 8;
      unsigned long long qlo = __hip_atomic_load((unsigned long long*)hsrc,
                                                 __ATOMIC_RELAXED, __HIP_MEMORY_SCOPE_AGENT);
      unsigned long long qhi = __hip_atomic_load(((unsigned long long*)hsrc) + 1,
                                                 __ATOMIC_RELAXED, __HIP_MEMORY_SCOPE_AGENT);
      U128 u; u.a = qlo; u.b = qhi;
      half8 af = __builtin_bit_cast(half8, u);
#pragma unroll
      for (int gt = 0; gt < 4; ++gt)
        acc[gt] = __builtin_amdgcn_mfma_f32_16x16x32_f16(af, wf[gt][kk], acc[gt], 0, 0, 0);
    }
#pragma unroll
    for (int gt = 0; gt < 4; ++gt)
#pragma unroll
      for (int rr = 0; rr < 4; ++rr)
        part[w][gt][quad * 4 + rr][l16] = acc[gt][rr];
    __syncthreads();

    {  // cross-wave K reduction: wave w -> gate w&3, row-half w>>2
      int gt = w & 3, rh = w >> 2;
#pragma unroll
      for (int rr = 2 * rh; rr < 2 * rh + 2; ++rr) {
        int m = quad * 4 + rr;
        float sum = part[0][gt][m][l16];
#pragma unroll
        for (int w2 = 1; w2 < 8; ++w2) sum += part[w2][gt][m][l16];
        red[gt][m][l16] = sum;
      }
    }
    __syncthreads();

    if (w < 4) {  // finalization: 4 waves x 64 lanes = 256 (m,n) cells
      int m = fm, n = l16;
      float iv = red[0][m][n] + pxi;
      float fv = red[1][m][n] + pxf;
      float gv = red[2][m][n] + pxg;
      float ov = red[3][m][n] + pxo;
      float si = 1.f / (1.f + __expf(-iv));
      float sf = 1.f / (1.f + __expf(-fv));
      float so = 1.f / (1.f + __expf(-ov));
      float ag = fabsf(gv), eg = __expf(-2.f * ag);
      float tg = (1.f - eg) / (1.f + eg);
      tg = (gv < 0.f) ? -tg : tg;
      float c = sf * cs[m][n] + si * tg;
      cs[m][n] = c;
      float ac = fabsf(c), ec = __expf(-2.f * ac);
      float th = (1.f - ec) / (1.f + ec);
      th = (c < 0.f) ? -th : th;
      float h = so * th;
      // h ping-pong store: packed 2xfp16, agent-coherent (sc1 write-through)
      unsigned short hu = __builtin_bit_cast(unsigned short, (_Float16)h);
      unsigned other = __shfl_xor((unsigned)hu, 1, 64);
      if ((l16 & 1) == 0) {
        unsigned packed = (unsigned)hu | (other << 16);
        __hip_atomic_store((unsigned*)(hnx + (size_t)(b0 + m) * H_ + u0 + l16), packed,
                           __ATOMIC_RELAXED, __HIP_MEMORY_SCOPE_AGENT);
      }
      size_t oidx = ((size_t)(b0 + m) * T_ + s) * H_ + u0 + n;
      if (out16) out16[oidx] = (_Float16)h;
      if (out32) out32[oidx] = h;
      if (s == T_ - 1) {
        hn_out[(size_t)(b0 + m) * H_ + u0 + n] = h;
        cn_out[(size_t)(b0 + m) * H_ + u0 + n] = c;
      }
    }
    __syncthreads();  // compiler emits s_waitcnt vmcnt(0) before s_barrier: h stores drained

    unsigned int tgt = 64u * (unsigned)(s + 1);
    if (w == 0) {
      if (lane == 0)
        __hip_atomic_fetch_add(cnt, 1u, __ATOMIC_RELAXED, __HIP_MEMORY_SCOPE_AGENT);
      // whole wave spins uniformly on same address -> 1 coalesced request/poll
      while (__hip_atomic_load(cnt, __ATOMIC_RELAXED, __HIP_MEMORY_SCOPE_AGENT) < tgt)
        __builtin_amdgcn_s_sleep(1);
      asm volatile("" ::: "memory");  // block compiler hoisting next step's loads
      if (lane == 0) __atomic_store_n(&step_flag, s + 1, __ATOMIC_RELEASE);
    } else {
      while (__atomic_load_n(&step_flag, __ATOMIC_ACQUIRE) < s + 1)
        __builtin_amdgcn_s_sleep(1);
    }
  }
}

// ---------------- host ----------------
extern "C" void kernel_launch(void* const* d_in, const int* in_sizes, int n_in,
                              void* d_out, int out_size, void* d_ws, size_t ws_size,
                              hipStream_t stream) {
  (void)in_sizes; (void)n_in; (void)out_size;
  const float* X    = (const float*)d_in[0];
  const float* Wih0 = (const float*)d_in[1];
  const float* bih0 = (const float*)d_in[2];
  const float* Whh0 = (const float*)d_in[3];
  const float* bhh0 = (const float*)d_in[4];
  const float* Wih1 = (const float*)d_in[5];
  const float* bih1 = (const float*)d_in[6];
  const float* Whh1 = (const float*)d_in[7];
  const float* bhh1 = (const float*)d_in[8];
  float* out = (float*)d_out;
  char* ws = (char*)d_ws;

  // ws layout (bytes):
  constexpr size_t SZW = (size_t)G_ * K_ * 2;  // 8 MB per packed weight
  constexpr size_t OFF_B0   = 4 * SZW;
  constexpr size_t OFF_B1   = OFF_B0 + 16384;
  constexpr size_t OFF_CNT  = OFF_B1 + 16384;
  constexpr size_t OFF_HBUF = OFF_CNT + 512;
  constexpr size_t OFF_OUT0 = OFF_HBUF + 4 * 131072;
  constexpr size_t OFF_XG   = OFF_OUT0 + (size_t)MPROJ * H_ * 2;
  constexpr size_t NEED     = OFF_XG + (size_t)MPROJ * G_ * 2;
  if (ws_size < NEED) return;  // fail visibly rather than corrupt

  _Float16* Wih0h = (_Float16*)(ws + 0 * SZW);
  _Float16* Whh0h = (_Float16*)(ws + 1 * SZW);
  _Float16* Wih1h = (_Float16*)(ws + 2 * SZW);
  _Float16* Whh1h = (_Float16*)(ws + 3 * SZW);
  float* b0s = (float*)(ws + OFF_B0);
  float* b1s = (float*)(ws + OFF_B1);
  unsigned int* cnts = (unsigned int*)(ws + OFF_CNT);
  _Float16* hbase = (_Float16*)(ws + OFF_HBUF);
  _Float16* hb00 = hbase;
  _Float16* hb01 = hbase + 65536;
  _Float16* hb10 = hbase + 131072;
  _Float16* hb11 = hbase + 196608;
  _Float16* out0h = (_Float16*)(ws + OFF_OUT0);
  _Float16* xgp   = (_Float16*)(ws + OFF_XG);

  // prep: pack weights to fp16, fold biases, zero h/counters
  k_f32_to_f16<<<4096, 256, 0, stream>>>(Wih0, Wih0h, G_ * K_ / 4);
  k_f32_to_f16<<<4096, 256, 0, stream>>>(Whh0, Whh0h, G_ * K_ / 4);
  k_f32_to_f16<<<4096, 256, 0, stream>>>(Wih1, Wih1h, G_ * K_ / 4);
  k_f32_to_f16<<<4096, 256, 0, stream>>>(Whh1, Whh1h, G_ * K_ / 4);
  k_bias<<<16, 256, 0, stream>>>(bih0, bhh0, bih1, bhh1, b0s, b1s);
  k_zero<<<129, 256, 0, stream>>>((uint4*)(ws + OFF_CNT), (512 + 4 * 131072) / 16);

  const int projGrid = (MPROJ / 128) * (G_ / 128);  // 8192

  // layer 0
  k_proj<float><<<dim3(projGrid), dim3(256), 0, stream>>>(X, Wih0h, b0s, xgp);
  {
    const _Float16* a0 = xgp;
    const _Float16* a1 = Whh0h;
    _Float16* a2 = hb00;
    _Float16* a3 = hb01;
    unsigned int* a4 = cnts;
    _Float16* a5 = out0h;
    float* a6 = nullptr;
    float* a7 = out + 33554432;            // h_n[0]
    float* a8 = out + 33554432 + 131072;   // c_n[0]
    void* args[9] = {&a0, &a1, &a2, &a3, &a4, &a5, &a6, &a7, &a8};
    hipLaunchCooperativeKernel((void*)k_rec, dim3(256), dim3(512), args, 0, stream);
  }

  // layer 1
  k_proj<_Float16><<<dim3(projGrid), dim3(256), 0, stream>>>(out0h, Wih1h, b1s, xgp);
  {
    const _Float16* a0 = xgp;
    const _Float16* a1 = Whh1h;
    _Float16* a2 = hb10;
    _Float16* a3 = hb11;
    unsigned int* a4 = cnts + 64;
    _Float16* a5 = nullptr;
    float* a6 = out;                               // out1
    float* a7 = out + 33554432 + 65536;            // h_n[1]
    float* a8 = out + 33554432 + 131072 + 65536;   // c_n[1]
    void* args[9] = {&a0, &a1, &a2, &a3, &a4, &a5, &a6, &a7, &a8};
    hipLaunchCooperativeKernel((void*)k_rec, dim3(256), dim3(512), args, 0, stream);
  }
}